// Round 7
// baseline (10276.730 us; speedup 1.0000x reference)
//
#include <hip/hip_runtime.h>
#include <math.h>

// ---------- helpers ----------
__device__ __forceinline__ float wsum64(float v) {
#pragma unroll
  for (int m = 32; m > 0; m >>= 1) v += __shfl_xor(v, m, 64);
  return v;
}
__device__ __forceinline__ float silu_f(float x) { return x / (1.0f + __expf(-x)); }

// LayerNorm across a 64-lane wave (one value per lane), eps=1e-5
__device__ __forceinline__ float ln64(float v, float g, float b) {
  float s  = wsum64(v);
  float s2 = wsum64(v * v);
  float m   = s * 0.015625f;                       // /64
  float var = fmaxf(s2 * 0.015625f - m * m, 0.0f);
  return (v - m) * rsqrtf(var + 1e-5f) * g + b;
}

// ---------- node embedding: h = silu(LN(x @ ne_w + ne_b)) ----------
__global__ __launch_bounds__(256) void k_node_embed(
    const float* __restrict__ x, const float* __restrict__ W,
    const float* __restrict__ b, const float* __restrict__ g,
    const float* __restrict__ be, float* __restrict__ h, int n) {
  int row = (blockIdx.x * 256 + threadIdx.x) >> 6;
  int j = threadIdx.x & 63;
  if (row >= n) return;
  const float* xr = x + (size_t)row * 16;
  float acc = b[j];
#pragma unroll
  for (int k = 0; k < 16; k += 4) {
    float4 xv = *(const float4*)&xr[k];
    acc += xv.x * W[(k + 0) * 64 + j] + xv.y * W[(k + 1) * 64 + j] +
           xv.z * W[(k + 2) * 64 + j] + xv.w * W[(k + 3) * 64 + j];
  }
  float v = ln64(acc, g[j], be[j]);
  h[(size_t)row * 64 + j] = silu_f(v);
}

// ---------- per-node msg weights: hw1 = h@W[0:64], hw2 = h@W[64:128] ----------
__global__ __launch_bounds__(256) void k_node_msgw(
    const float* __restrict__ h, const float* __restrict__ W,
    float* __restrict__ hw1, float* __restrict__ hw2, int n) {
  int row = (blockIdx.x * 256 + threadIdx.x) >> 6;
  int j = threadIdx.x & 63;
  if (row >= n) return;
  const float* hr = h + (size_t)row * 64;
  float a1 = 0.0f, a2 = 0.0f;
#pragma unroll
  for (int k = 0; k < 64; k += 4) {
    float4 hv = *(const float4*)&hr[k];
    a1 += hv.x * W[(k + 0) * 64 + j] + hv.y * W[(k + 1) * 64 + j] +
          hv.z * W[(k + 2) * 64 + j] + hv.w * W[(k + 3) * 64 + j];
    a2 += hv.x * W[(64 + k + 0) * 64 + j] + hv.y * W[(64 + k + 1) * 64 + j] +
          hv.z * W[(64 + k + 2) * 64 + j] + hv.w * W[(64 + k + 3) * 64 + j];
  }
  hw1[(size_t)row * 64 + j] = a1;
  hw2[(size_t)row * 64 + j] = a2;
}

// ---------- SPLIT kernel A: ew3[r] = silu(LN(ea[r]@eeW)) @ W3 + msg_b ----------
// Register budget FORCED via launch_bounds min-waves: 4 waves/EU -> VGPR<=128.
// True live state is ~60-80 regs; the cap stops the scheduler from
// prefetch-exploding past 256 into scratch (rounds 4/6 failure mode).
#define RPW 8
__global__ __launch_bounds__(256, 4) void k_edge_w3(
    const float* __restrict__ ea, const float* __restrict__ eeW,
    const float* __restrict__ eeB, const float* __restrict__ eeG,
    const float* __restrict__ eeBe,
    const float* __restrict__ W3, const float* __restrict__ msgB,
    float* __restrict__ ew3, int nedges) {
  __shared__ float sW3[64 * 64];        // 16 KB
  __shared__ float sE[4][RPW][64];      // 8 KB
  __shared__ float sEA[4][RPW * 8];     // 1 KB: 8 edges x 8 attrs per wave

  for (int idx = threadIdx.x * 4; idx < 64 * 64; idx += 1024)
    *(float4*)&sW3[idx] = *(const float4*)&W3[idx];

  const int wv = threadIdx.x >> 6;
  const int j  = threadIdx.x & 63;
  const int rbase = (blockIdx.x * 4 + wv) * RPW;

  // cooperative attr staging: 64 lanes fetch 8 edges x 8 attrs in one load
  {
    long long ai = (long long)rbase * 8 + j;
    long long amax = (long long)nedges * 8 - 1;
    if (ai > amax) ai = amax;
    sEA[wv][j] = ea[ai];
  }
  __syncthreads();   // sW3 ready (and sEA, trivially same-wave)

  if (rbase >= nedges) return;

  // eeW column j (8 coalesced loads, cached)
  float ewc[8];
#pragma unroll
  for (int k = 0; k < 8; ++k) ewc[k] = eeW[k * 64 + j];

  const float eb = eeB[j], eg = eeG[j], ebe = eeBe[j];
#pragma unroll
  for (int r = 0; r < RPW; ++r) {
    const float* ar = &sEA[wv][r * 8];   // LDS broadcast reads
    float ev = eb;
#pragma unroll
    for (int k = 0; k < 8; ++k) ev += ar[k] * ewc[k];
    ev = silu_f(ln64(ev, eg, ebe));
    sE[wv][r][j] = ev;   // same-wave write, same-wave read below -> ordered
  }

  float acc[RPW];
  const float bj = msgB[j];
#pragma unroll
  for (int r = 0; r < RPW; ++r) acc[r] = bj;

#pragma unroll
  for (int k = 0; k < 64; k += 4) {
    float w0 = sW3[(k + 0) * 64 + j];   // stride-1 across lanes: conflict-free
    float w1 = sW3[(k + 1) * 64 + j];
    float w2 = sW3[(k + 2) * 64 + j];
    float w3 = sW3[(k + 3) * 64 + j];
#pragma unroll
    for (int r = 0; r < RPW; ++r) {
      float4 ev4 = *(const float4*)&sE[wv][r][k];   // broadcast read
      acc[r] += ev4.x * w0 + ev4.y * w1 + ev4.z * w2 + ev4.w * w3;
    }
  }

#pragma unroll
  for (int r = 0; r < RPW; ++r)
    if (rbase + r < nedges) ew3[(size_t)(rbase + r) * 64 + j] = acc[r];
}

// ---------- SPLIT kernel B: m = LN(silu(ew3+hw1[dst]+hw2[src])); agg[dst]+=m ----------
#define EPB 8
__global__ __launch_bounds__(256, 2) void k_edge_scatter(
    const float* __restrict__ ew3, const float* __restrict__ hw1,
    const float* __restrict__ hw2, const float* __restrict__ msgG,
    const float* __restrict__ msgBe,
    const int* __restrict__ srcI, const int* __restrict__ dstI,
    float* __restrict__ agg, int nedges) {
  const int wv = threadIdx.x >> 6;
  const int j  = threadIdx.x & 63;
  const int ebase = (blockIdx.x * 4 + wv) * EPB;
  if (ebase >= nedges) return;

  int dIdx[EPB];
  float acc[EPB];
#pragma unroll
  for (int e = 0; e < EPB; ++e) {
    int ce = min(ebase + e, nedges - 1);
    int s = srcI[ce];
    dIdx[e] = dstI[ce];
    acc[e] = ew3[(size_t)ce * 64 + j] + hw1[(size_t)dIdx[e] * 64 + j] +
             hw2[(size_t)s * 64 + j];
  }
  const float mg = msgG[j], mbe = msgBe[j];
#pragma unroll
  for (int e = 0; e < EPB; ++e) {
    float m = ln64(silu_f(acc[e]), mg, mbe);
    if (ebase + e < nedges) unsafeAtomicAdd(&agg[(size_t)dIdx[e] * 64 + j], m);
  }
}

// ---------- FUSED FALLBACK (ws too small): round-1 proven structure, EPW=4 ----------
#define EPW 4
__global__ __launch_bounds__(256) void k_edge_msg(
    const float* __restrict__ ea, const float* __restrict__ eeW,
    const float* __restrict__ eeB, const float* __restrict__ eeG,
    const float* __restrict__ eeBe,
    const float* __restrict__ W3, const float* __restrict__ msgB,
    const float* __restrict__ msgG, const float* __restrict__ msgBe,
    const float* __restrict__ hw1, const float* __restrict__ hw2,
    const int* __restrict__ srcI, const int* __restrict__ dstI,
    float* __restrict__ agg, int nedges) {
  __shared__ float sW3[64 * 64];
  __shared__ float sE[4][EPW][64];

  for (int idx = threadIdx.x * 4; idx < 64 * 64; idx += 1024)
    *(float4*)&sW3[idx] = *(const float4*)&W3[idx];
  __syncthreads();

  const int wv = threadIdx.x >> 6;
  const int j  = threadIdx.x & 63;
  const int ebase = (blockIdx.x * 4 + wv) * EPW;
  if (ebase >= nedges) return;

  const float bj = msgB[j];
  int dIdx[EPW];
  float acc[EPW];
#pragma unroll
  for (int e = 0; e < EPW; ++e) {
    int ce = min(ebase + e, nedges - 1);
    int s = srcI[ce];
    dIdx[e] = dstI[ce];
    acc[e] = hw1[(size_t)dIdx[e] * 64 + j] + hw2[(size_t)s * 64 + j] + bj;
  }
  {
    const float eb = eeB[j], eg = eeG[j], ebe = eeBe[j];
#pragma unroll
    for (int e = 0; e < EPW; ++e) {
      int ce = min(ebase + e, nedges - 1);
      const float* ear = ea + (size_t)ce * 8;
      float4 a0 = *(const float4*)&ear[0];
      float4 a1 = *(const float4*)&ear[4];
      float ev = eb;
      ev += a0.x * eeW[0 * 64 + j] + a0.y * eeW[1 * 64 + j] +
            a0.z * eeW[2 * 64 + j] + a0.w * eeW[3 * 64 + j];
      ev += a1.x * eeW[4 * 64 + j] + a1.y * eeW[5 * 64 + j] +
            a1.z * eeW[6 * 64 + j] + a1.w * eeW[7 * 64 + j];
      ev = silu_f(ln64(ev, eg, ebe));
      sE[wv][e][j] = ev;
    }
  }
#pragma unroll
  for (int k = 0; k < 64; k += 4) {
    float w0 = sW3[(k + 0) * 64 + j];
    float w1 = sW3[(k + 1) * 64 + j];
    float w2 = sW3[(k + 2) * 64 + j];
    float w3 = sW3[(k + 3) * 64 + j];
#pragma unroll
    for (int e = 0; e < EPW; ++e) {
      float4 ev4 = *(const float4*)&sE[wv][e][k];
      acc[e] += ev4.x * w0 + ev4.y * w1 + ev4.z * w2 + ev4.w * w3;
    }
  }
  {
    const float mg = msgG[j], mbe = msgBe[j];
#pragma unroll
    for (int e = 0; e < EPW; ++e) {
      float m = ln64(silu_f(acc[e]), mg, mbe);
      if (ebase + e < nedges) unsafeAtomicAdd(&agg[(size_t)dIdx[e] * 64 + j], m);
    }
  }
}

// ---------- update: hn = LN(LN(silu((h+agg)@W+b)) + h) ----------
__global__ __launch_bounds__(256) void k_node_update(
    const float* __restrict__ h, const float* __restrict__ agg,
    const float* __restrict__ W, const float* __restrict__ b,
    const float* __restrict__ ug, const float* __restrict__ ube,
    const float* __restrict__ ng, const float* __restrict__ nbe,
    float* __restrict__ hn, int n) {
  int row = (blockIdx.x * 256 + threadIdx.x) >> 6;
  int j = threadIdx.x & 63;
  if (row >= n) return;
  const float* hr = h + (size_t)row * 64;
  const float* ar = agg + (size_t)row * 64;
  float acc = b[j];
#pragma unroll
  for (int k = 0; k < 64; k += 4) {
    float4 hv = *(const float4*)&hr[k];
    float4 av = *(const float4*)&ar[k];
    acc += (hv.x + av.x) * W[(k + 0) * 64 + j] + (hv.y + av.y) * W[(k + 1) * 64 + j] +
           (hv.z + av.z) * W[(k + 2) * 64 + j] + (hv.w + av.w) * W[(k + 3) * 64 + j];
  }
  float u = ln64(silu_f(acc), ug[j], ube[j]);
  hn[(size_t)row * 64 + j] = ln64(u + hr[j], ng[j], nbe[j]);
}

// ---------- pooling ----------
__global__ __launch_bounds__(256) void k_pool(
    const float* __restrict__ h, const int* __restrict__ batch,
    float* __restrict__ gsum, float* __restrict__ gcnt, int n) {
  int row = (blockIdx.x * 256 + threadIdx.x) >> 6;
  int j = threadIdx.x & 63;
  if (row >= n) return;
  int b = batch[row];
  unsafeAtomicAdd(&gsum[(size_t)b * 64 + j], h[(size_t)row * 64 + j]);
  if (j == 0) unsafeAtomicAdd(&gcnt[b], 1.0f);
}

// ---------- head: out = silu(LN(g@h1_w+b)) @ h2_w + h2_b ----------
__global__ __launch_bounds__(64) void k_head(
    const float* __restrict__ gsum, const float* __restrict__ gcnt,
    const float* __restrict__ w1, const float* __restrict__ b1,
    const float* __restrict__ g1, const float* __restrict__ be1,
    const float* __restrict__ w2, const float* __restrict__ b2,
    float* __restrict__ out, int ngraphs) {
  int gidx = blockIdx.x;
  int j = threadIdx.x;
  if (gidx >= ngraphs) return;
  __shared__ float sg[64];
  float cnt = fmaxf(gcnt[gidx], 1.0f);
  sg[j] = gsum[(size_t)gidx * 64 + j] / cnt;
  float acc = 0.0f;
  if (j < 32) {
    acc = b1[j];
#pragma unroll 8
    for (int k = 0; k < 64; ++k) acc += sg[k] * w1[k * 32 + j];
  }
  float s = acc, s2 = acc * acc;
#pragma unroll
  for (int m = 16; m > 0; m >>= 1) {
    s  += __shfl_xor(s,  m, 64);
    s2 += __shfl_xor(s2, m, 64);
  }
  float mean = s * 0.03125f;
  float var  = fmaxf(s2 * 0.03125f - mean * mean, 0.0f);
  float z = 0.0f;
  if (j < 32) {
    float nv = (acc - mean) * rsqrtf(var + 1e-5f) * g1[j] + be1[j];
    z = silu_f(nv) * w2[j];
  }
  float tot = wsum64(z);
  if (j == 0) out[gidx] = tot + b2[0];
}

// ---------- launch ----------
extern "C" void kernel_launch(void* const* d_in, const int* in_sizes, int n_in,
                              void* d_out, int out_size, void* d_ws, size_t ws_size,
                              hipStream_t stream) {
  const float* x      = (const float*)d_in[0];
  const float* ea     = (const float*)d_in[1];
  const float* ne_w   = (const float*)d_in[2];
  const float* ne_b   = (const float*)d_in[3];
  const float* ne_g   = (const float*)d_in[4];
  const float* ne_be  = (const float*)d_in[5];
  const float* ee_w   = (const float*)d_in[6];
  const float* ee_b   = (const float*)d_in[7];
  const float* ee_g   = (const float*)d_in[8];
  const float* ee_be  = (const float*)d_in[9];
  const float* msg_w  = (const float*)d_in[10];
  const float* msg_b  = (const float*)d_in[11];
  const float* msg_g  = (const float*)d_in[12];
  const float* msg_be = (const float*)d_in[13];
  const float* upd_w  = (const float*)d_in[14];
  const float* upd_b  = (const float*)d_in[15];
  const float* upd_g  = (const float*)d_in[16];
  const float* upd_be = (const float*)d_in[17];
  const float* nrm_g  = (const float*)d_in[18];
  const float* nrm_be = (const float*)d_in[19];
  const float* h1_w   = (const float*)d_in[20];
  const float* h1_b   = (const float*)d_in[21];
  const float* h1_g   = (const float*)d_in[22];
  const float* h1_be  = (const float*)d_in[23];
  const float* h2_w   = (const float*)d_in[24];
  const float* h2_b   = (const float*)d_in[25];
  const int*   ei     = (const int*)d_in[26];
  const int*   batch  = (const int*)d_in[27];
  float* out = (float*)d_out;

  const int N = in_sizes[0] / 16;
  const int E = in_sizes[1] / 8;
  const int G = out_size;
  const int* srcI = ei;       // edge_index[0] = src (x_j)
  const int* dstI = ei + E;   // edge_index[1] = dst (x_i)

  float* ws  = (float*)d_ws;
  float* h    = ws;
  float* hn   = h   + (size_t)N * 64;
  float* hw1  = hn  + (size_t)N * 64;
  float* hw2  = hw1 + (size_t)N * 64;
  float* agg  = hw2 + (size_t)N * 64;
  float* gsum = agg + (size_t)N * 64;
  float* gcnt = gsum + (size_t)G * 64;
  float* ew3  = gcnt + G;                 // chunked [chunkE,64] scratch

  // size the ew3 chunk to whatever workspace is actually available
  const size_t fixed_floats = (size_t)N * 64 * 5 + (size_t)G * 64 + G;
  long long avail = (long long)(ws_size / 4) - (long long)fixed_floats;
  int chunkE = 0;
  if (avail > 0) {
    long long c = avail / 64;
    chunkE = (int)((c > E) ? E : c);
    chunkE &= ~31;                        // keep wave-tile aligned
  }
  const bool split = (chunkE >= 32768);

  const int nblk = (N + 3) / 4;                      // 4 node rows per block
  const int eblkF = (E + 4 * EPW - 1) / (4 * EPW);   // fused fallback blocks

  k_node_embed<<<nblk, 256, 0, stream>>>(x, ne_w, ne_b, ne_g, ne_be, h, N);

  float* hcur = h;
  float* hnext = hn;
  for (int l = 0; l < 2; ++l) {
    const float* Wl = msg_w + (size_t)l * 192 * 64;
    k_node_msgw<<<nblk, 256, 0, stream>>>(hcur, Wl, hw1, hw2, N);
    hipMemsetAsync(agg, 0, (size_t)N * 64 * sizeof(float), stream);
    if (split) {
      for (int c0 = 0; c0 < E; c0 += chunkE) {
        int ce = (E - c0 < chunkE) ? (E - c0) : chunkE;
        int ba = (ce + 4 * RPW - 1) / (4 * RPW);
        int bb = (ce + 4 * EPB - 1) / (4 * EPB);
        k_edge_w3<<<ba, 256, 0, stream>>>(
            ea + (size_t)c0 * 8, ee_w, ee_b, ee_g, ee_be,
            Wl + 128 * 64, msg_b + l * 64, ew3, ce);
        k_edge_scatter<<<bb, 256, 0, stream>>>(
            ew3, hw1, hw2, msg_g + l * 64, msg_be + l * 64,
            srcI + c0, dstI + c0, agg, ce);
      }
    } else {
      k_edge_msg<<<eblkF, 256, 0, stream>>>(
          ea, ee_w, ee_b, ee_g, ee_be,
          Wl + 128 * 64, msg_b + l * 64, msg_g + l * 64, msg_be + l * 64,
          hw1, hw2, srcI, dstI, agg, E);
    }
    k_node_update<<<nblk, 256, 0, stream>>>(
        hcur, agg, upd_w + (size_t)l * 64 * 64,
        upd_b + l * 64, upd_g + l * 64, upd_be + l * 64,
        nrm_g + l * 64, nrm_be + l * 64, hnext, N);
    float* t = hcur; hcur = hnext; hnext = t;
  }

  hipMemsetAsync(gsum, 0, ((size_t)G * 64 + G) * sizeof(float), stream);
  k_pool<<<nblk, 256, 0, stream>>>(hcur, batch, gsum, gcnt, N);
  k_head<<<G, 64, 0, stream>>>(gsum, gcnt, h1_w, h1_b, h1_g, h1_be, h2_w, h2_b, out, G);
}

// Round 8
// 1568.467 us; speedup vs baseline: 6.5521x; 6.5521x over previous
//
#include <hip/hip_runtime.h>
#include <math.h>

// ---------- helpers ----------
__device__ __forceinline__ float wsum64(float v) {
#pragma unroll
  for (int m = 32; m > 0; m >>= 1) v += __shfl_xor(v, m, 64);
  return v;
}
__device__ __forceinline__ float silu_f(float x) { return x / (1.0f + __expf(-x)); }

// LayerNorm across a 64-lane wave (one value per lane), eps=1e-5
__device__ __forceinline__ float ln64(float v, float g, float b) {
  float s  = wsum64(v);
  float s2 = wsum64(v * v);
  float m   = s * 0.015625f;                       // /64
  float var = fmaxf(s2 * 0.015625f - m * m, 0.0f);
  return (v - m) * rsqrtf(var + 1e-5f) * g + b;
}

// ---------- node embedding: h = silu(LN(x @ ne_w + ne_b)) ----------
__global__ __launch_bounds__(256) void k_node_embed(
    const float* __restrict__ x, const float* __restrict__ W,
    const float* __restrict__ b, const float* __restrict__ g,
    const float* __restrict__ be, float* __restrict__ h, int n) {
  int row = (blockIdx.x * 256 + threadIdx.x) >> 6;
  int j = threadIdx.x & 63;
  if (row >= n) return;
  const float* xr = x + (size_t)row * 16;
  float acc = b[j];
#pragma unroll
  for (int k = 0; k < 16; k += 4) {
    float4 xv = *(const float4*)&xr[k];
    acc += xv.x * W[(k + 0) * 64 + j] + xv.y * W[(k + 1) * 64 + j] +
           xv.z * W[(k + 2) * 64 + j] + xv.w * W[(k + 3) * 64 + j];
  }
  float v = ln64(acc, g[j], be[j]);
  h[(size_t)row * 64 + j] = silu_f(v);
}

// ---------- per-node msg weights: hw1 = h@W[0:64], hw2 = h@W[64:128] ----------
__global__ __launch_bounds__(256) void k_node_msgw(
    const float* __restrict__ h, const float* __restrict__ W,
    float* __restrict__ hw1, float* __restrict__ hw2, int n) {
  int row = (blockIdx.x * 256 + threadIdx.x) >> 6;
  int j = threadIdx.x & 63;
  if (row >= n) return;
  const float* hr = h + (size_t)row * 64;
  float a1 = 0.0f, a2 = 0.0f;
#pragma unroll
  for (int k = 0; k < 64; k += 4) {
    float4 hv = *(const float4*)&hr[k];
    a1 += hv.x * W[(k + 0) * 64 + j] + hv.y * W[(k + 1) * 64 + j] +
          hv.z * W[(k + 2) * 64 + j] + hv.w * W[(k + 3) * 64 + j];
    a2 += hv.x * W[(64 + k + 0) * 64 + j] + hv.y * W[(64 + k + 1) * 64 + j] +
          hv.z * W[(64 + k + 2) * 64 + j] + hv.w * W[(64 + k + 3) * 64 + j];
  }
  hw1[(size_t)row * 64 + j] = a1;
  hw2[(size_t)row * 64 + j] = a2;
}

// ---------- fused edge kernel (round-1 proven structure, EPW=4) ----------
// m = LN(silu(hw1[dst] + hw2[src] + e@W3 + msg_b)); agg[dst] += m
// + cooperative coalesced staging of edge attrs (16 edges x 8 attrs / block)
#define EPW 4
__global__ __launch_bounds__(256) void k_edge_msg(
    const float* __restrict__ ea, const float* __restrict__ eeW,
    const float* __restrict__ eeB, const float* __restrict__ eeG,
    const float* __restrict__ eeBe,
    const float* __restrict__ W3, const float* __restrict__ msgB,
    const float* __restrict__ msgG, const float* __restrict__ msgBe,
    const float* __restrict__ hw1, const float* __restrict__ hw2,
    const int* __restrict__ srcI, const int* __restrict__ dstI,
    float* __restrict__ agg, int nedges) {
  __shared__ float sW3[64 * 64];       // 16 KB
  __shared__ float sE[4][EPW][64];     // 4 KB
  __shared__ float sEA[16][9];         // 16 edges x 8 attrs, 9-padded (0.6 KB)

  // stage W3 (coalesced float4)
  for (int idx = threadIdx.x * 4; idx < 64 * 64; idx += 1024)
    *(float4*)&sW3[idx] = *(const float4*)&W3[idx];

  // stage 16 edges x 8 attrs with ONE coalesced 128-lane load
  {
    int t = threadIdx.x;
    if (t < 128) {
      long long gi = (long long)blockIdx.x * 128 + t;     // = edge*8 + attr
      long long gmax = (long long)nedges * 8 - 1;
      if (gi > gmax) gi = gmax;
      sEA[t >> 3][t & 7] = ea[gi];
    }
  }
  __syncthreads();

  const int wv = threadIdx.x >> 6;
  const int j  = threadIdx.x & 63;
  const int ebase = (blockIdx.x * 4 + wv) * EPW;
  if (ebase >= nedges) return;

  // issue index loads + hw1/hw2 gathers first (long-latency, overlap embed)
  const float bj = msgB[j];
  int dIdx[EPW];
  float acc[EPW];
#pragma unroll
  for (int e = 0; e < EPW; ++e) {
    int ce = min(ebase + e, nedges - 1);
    int s = srcI[ce];
    dIdx[e] = dstI[ce];
    acc[e] = hw1[(size_t)dIdx[e] * 64 + j] + hw2[(size_t)s * 64 + j] + bj;
  }

  // edge embeddings from LDS-staged attrs (broadcast reads, no global latency)
  {
    float ewc[8];
#pragma unroll
    for (int k = 0; k < 8; ++k) ewc[k] = eeW[k * 64 + j];
    const float eb = eeB[j], eg = eeG[j], ebe = eeBe[j];
#pragma unroll
    for (int e = 0; e < EPW; ++e) {
      const float* ar = &sEA[wv * EPW + e][0];
      float ev = eb;
#pragma unroll
      for (int k = 0; k < 8; ++k) ev += ar[k] * ewc[k];
      ev = silu_f(ln64(ev, eg, ebe));
      sE[wv][e][j] = ev;   // same-wave write; same-wave read below -> ordered
    }
  }

  // MAC: acc[e] += e_vec @ W3
#pragma unroll
  for (int k = 0; k < 64; k += 4) {
    float w0 = sW3[(k + 0) * 64 + j];
    float w1 = sW3[(k + 1) * 64 + j];
    float w2 = sW3[(k + 2) * 64 + j];
    float w3 = sW3[(k + 3) * 64 + j];
#pragma unroll
    for (int e = 0; e < EPW; ++e) {
      float4 ev4 = *(const float4*)&sE[wv][e][k];
      acc[e] += ev4.x * w0 + ev4.y * w1 + ev4.z * w2 + ev4.w * w3;
    }
  }

  // LN + silu + scatter-add
  {
    const float mg = msgG[j], mbe = msgBe[j];
#pragma unroll
    for (int e = 0; e < EPW; ++e) {
      float m = ln64(silu_f(acc[e]), mg, mbe);
      if (ebase + e < nedges) unsafeAtomicAdd(&agg[(size_t)dIdx[e] * 64 + j], m);
    }
  }
}

// ---------- update: hn = LN(LN(silu((h+agg)@W+b)) + h) ----------
__global__ __launch_bounds__(256) void k_node_update(
    const float* __restrict__ h, const float* __restrict__ agg,
    const float* __restrict__ W, const float* __restrict__ b,
    const float* __restrict__ ug, const float* __restrict__ ube,
    const float* __restrict__ ng, const float* __restrict__ nbe,
    float* __restrict__ hn, int n) {
  int row = (blockIdx.x * 256 + threadIdx.x) >> 6;
  int j = threadIdx.x & 63;
  if (row >= n) return;
  const float* hr = h + (size_t)row * 64;
  const float* ar = agg + (size_t)row * 64;
  float acc = b[j];
#pragma unroll
  for (int k = 0; k < 64; k += 4) {
    float4 hv = *(const float4*)&hr[k];
    float4 av = *(const float4*)&ar[k];
    acc += (hv.x + av.x) * W[(k + 0) * 64 + j] + (hv.y + av.y) * W[(k + 1) * 64 + j] +
           (hv.z + av.z) * W[(k + 2) * 64 + j] + (hv.w + av.w) * W[(k + 3) * 64 + j];
  }
  float u = ln64(silu_f(acc), ug[j], ube[j]);
  hn[(size_t)row * 64 + j] = ln64(u + hr[j], ng[j], nbe[j]);
}

// ---------- pooling ----------
__global__ __launch_bounds__(256) void k_pool(
    const float* __restrict__ h, const int* __restrict__ batch,
    float* __restrict__ gsum, float* __restrict__ gcnt, int n) {
  int row = (blockIdx.x * 256 + threadIdx.x) >> 6;
  int j = threadIdx.x & 63;
  if (row >= n) return;
  int b = batch[row];
  unsafeAtomicAdd(&gsum[(size_t)b * 64 + j], h[(size_t)row * 64 + j]);
  if (j == 0) unsafeAtomicAdd(&gcnt[b], 1.0f);
}

// ---------- head: out = silu(LN(g@h1_w+b)) @ h2_w + h2_b ----------
__global__ __launch_bounds__(64) void k_head(
    const float* __restrict__ gsum, const float* __restrict__ gcnt,
    const float* __restrict__ w1, const float* __restrict__ b1,
    const float* __restrict__ g1, const float* __restrict__ be1,
    const float* __restrict__ w2, const float* __restrict__ b2,
    float* __restrict__ out, int ngraphs) {
  int gidx = blockIdx.x;
  int j = threadIdx.x;
  if (gidx >= ngraphs) return;
  __shared__ float sg[64];
  float cnt = fmaxf(gcnt[gidx], 1.0f);
  sg[j] = gsum[(size_t)gidx * 64 + j] / cnt;
  float acc = 0.0f;
  if (j < 32) {
    acc = b1[j];
#pragma unroll 8
    for (int k = 0; k < 64; ++k) acc += sg[k] * w1[k * 32 + j];
  }
  float s = acc, s2 = acc * acc;
#pragma unroll
  for (int m = 16; m > 0; m >>= 1) {
    s  += __shfl_xor(s,  m, 64);
    s2 += __shfl_xor(s2, m, 64);
  }
  float mean = s * 0.03125f;
  float var  = fmaxf(s2 * 0.03125f - mean * mean, 0.0f);
  float z = 0.0f;
  if (j < 32) {
    float nv = (acc - mean) * rsqrtf(var + 1e-5f) * g1[j] + be1[j];
    z = silu_f(nv) * w2[j];
  }
  float tot = wsum64(z);
  if (j == 0) out[gidx] = tot + b2[0];
}

// ---------- launch ----------
extern "C" void kernel_launch(void* const* d_in, const int* in_sizes, int n_in,
                              void* d_out, int out_size, void* d_ws, size_t ws_size,
                              hipStream_t stream) {
  const float* x      = (const float*)d_in[0];
  const float* ea     = (const float*)d_in[1];
  const float* ne_w   = (const float*)d_in[2];
  const float* ne_b   = (const float*)d_in[3];
  const float* ne_g   = (const float*)d_in[4];
  const float* ne_be  = (const float*)d_in[5];
  const float* ee_w   = (const float*)d_in[6];
  const float* ee_b   = (const float*)d_in[7];
  const float* ee_g   = (const float*)d_in[8];
  const float* ee_be  = (const float*)d_in[9];
  const float* msg_w  = (const float*)d_in[10];
  const float* msg_b  = (const float*)d_in[11];
  const float* msg_g  = (const float*)d_in[12];
  const float* msg_be = (const float*)d_in[13];
  const float* upd_w  = (const float*)d_in[14];
  const float* upd_b  = (const float*)d_in[15];
  const float* upd_g  = (const float*)d_in[16];
  const float* upd_be = (const float*)d_in[17];
  const float* nrm_g  = (const float*)d_in[18];
  const float* nrm_be = (const float*)d_in[19];
  const float* h1_w   = (const float*)d_in[20];
  const float* h1_b   = (const float*)d_in[21];
  const float* h1_g   = (const float*)d_in[22];
  const float* h1_be  = (const float*)d_in[23];
  const float* h2_w   = (const float*)d_in[24];
  const float* h2_b   = (const float*)d_in[25];
  const int*   ei     = (const int*)d_in[26];
  const int*   batch  = (const int*)d_in[27];
  float* out = (float*)d_out;

  const int N = in_sizes[0] / 16;
  const int E = in_sizes[1] / 8;
  const int G = out_size;
  const int* srcI = ei;       // edge_index[0] = src (x_j)
  const int* dstI = ei + E;   // edge_index[1] = dst (x_i)

  float* ws  = (float*)d_ws;
  float* h    = ws;
  float* hn   = h   + (size_t)N * 64;
  float* hw1  = hn  + (size_t)N * 64;
  float* hw2  = hw1 + (size_t)N * 64;
  float* agg  = hw2 + (size_t)N * 64;
  float* gsum = agg + (size_t)N * 64;
  float* gcnt = gsum + (size_t)G * 64;

  const int nblk = (N + 3) / 4;                      // 4 node rows per block
  const int eblk = (E + 4 * EPW - 1) / (4 * EPW);    // 16 edges per block

  k_node_embed<<<nblk, 256, 0, stream>>>(x, ne_w, ne_b, ne_g, ne_be, h, N);

  float* hcur = h;
  float* hnext = hn;
  for (int l = 0; l < 2; ++l) {
    const float* Wl = msg_w + (size_t)l * 192 * 64;
    k_node_msgw<<<nblk, 256, 0, stream>>>(hcur, Wl, hw1, hw2, N);
    hipMemsetAsync(agg, 0, (size_t)N * 64 * sizeof(float), stream);
    k_edge_msg<<<eblk, 256, 0, stream>>>(
        ea, ee_w, ee_b, ee_g, ee_be,
        Wl + 128 * 64, msg_b + l * 64, msg_g + l * 64, msg_be + l * 64,
        hw1, hw2, srcI, dstI, agg, E);
    k_node_update<<<nblk, 256, 0, stream>>>(
        hcur, agg, upd_w + (size_t)l * 64 * 64,
        upd_b + l * 64, upd_g + l * 64, upd_be + l * 64,
        nrm_g + l * 64, nrm_be + l * 64, hnext, N);
    float* t = hcur; hcur = hnext; hnext = t;
  }

  hipMemsetAsync(gsum, 0, ((size_t)G * 64 + G) * sizeof(float), stream);
  k_pool<<<nblk, 256, 0, stream>>>(hcur, batch, gsum, gcnt, N);
  k_head<<<G, 64, 0, stream>>>(gsum, gcnt, h1_w, h1_b, h1_g, h1_be, h2_w, h2_b, out, G);
}

// Round 9
// 1433.924 us; speedup vs baseline: 7.1669x; 1.0938x over previous
//
#include <hip/hip_runtime.h>
#include <math.h>

// ---------- helpers ----------
__device__ __forceinline__ float wsum64(float v) {
#pragma unroll
  for (int m = 32; m > 0; m >>= 1) v += __shfl_xor(v, m, 64);
  return v;
}
__device__ __forceinline__ float silu_f(float x) { return x / (1.0f + __expf(-x)); }

// LayerNorm across a 64-lane wave (one value per lane), eps=1e-5
__device__ __forceinline__ float ln64(float v, float g, float b) {
  float s  = wsum64(v);
  float s2 = wsum64(v * v);
  float m   = s * 0.015625f;                       // /64
  float var = fmaxf(s2 * 0.015625f - m * m, 0.0f);
  return (v - m) * rsqrtf(var + 1e-5f) * g + b;
}

// ---------- node embedding: h = silu(LN(x @ ne_w + ne_b)) ----------
__global__ __launch_bounds__(256) void k_node_embed(
    const float* __restrict__ x, const float* __restrict__ W,
    const float* __restrict__ b, const float* __restrict__ g,
    const float* __restrict__ be, float* __restrict__ h, int n) {
  int row = (blockIdx.x * 256 + threadIdx.x) >> 6;
  int j = threadIdx.x & 63;
  if (row >= n) return;
  const float* xr = x + (size_t)row * 16;
  float acc = b[j];
#pragma unroll
  for (int k = 0; k < 16; k += 4) {
    float4 xv = *(const float4*)&xr[k];
    acc += xv.x * W[(k + 0) * 64 + j] + xv.y * W[(k + 1) * 64 + j] +
           xv.z * W[(k + 2) * 64 + j] + xv.w * W[(k + 3) * 64 + j];
  }
  float v = ln64(acc, g[j], be[j]);
  h[(size_t)row * 64 + j] = silu_f(v);
}

// ---------- per-node msg weights: hw1 = h@W[0:64], hw2 = h@W[64:128] ----------
__global__ __launch_bounds__(256) void k_node_msgw(
    const float* __restrict__ h, const float* __restrict__ W,
    float* __restrict__ hw1, float* __restrict__ hw2, int n) {
  int row = (blockIdx.x * 256 + threadIdx.x) >> 6;
  int j = threadIdx.x & 63;
  if (row >= n) return;
  const float* hr = h + (size_t)row * 64;
  float a1 = 0.0f, a2 = 0.0f;
#pragma unroll
  for (int k = 0; k < 64; k += 4) {
    float4 hv = *(const float4*)&hr[k];
    a1 += hv.x * W[(k + 0) * 64 + j] + hv.y * W[(k + 1) * 64 + j] +
          hv.z * W[(k + 2) * 64 + j] + hv.w * W[(k + 3) * 64 + j];
    a2 += hv.x * W[(64 + k + 0) * 64 + j] + hv.y * W[(64 + k + 1) * 64 + j] +
          hv.z * W[(64 + k + 2) * 64 + j] + hv.w * W[(64 + k + 3) * 64 + j];
  }
  hw1[(size_t)row * 64 + j] = a1;
  hw2[(size_t)row * 64 + j] = a2;
}

// ---------- fused edge kernel: barrier-free, per-wave independent ----------
// m = LN(silu(hw1[dst] + hw2[src] + e@W3 + msg_b)); agg[dst] += m
// W3 read directly from global (L1-resident 16 KB); attrs staged per-wave.
#define EPW 4
__global__ __launch_bounds__(256) void k_edge_msg(
    const float* __restrict__ ea, const float* __restrict__ eeW,
    const float* __restrict__ eeB, const float* __restrict__ eeG,
    const float* __restrict__ eeBe,
    const float* __restrict__ W3, const float* __restrict__ msgB,
    const float* __restrict__ msgG, const float* __restrict__ msgBe,
    const float* __restrict__ hw1, const float* __restrict__ hw2,
    const int* __restrict__ srcI, const int* __restrict__ dstI,
    float* __restrict__ agg, int nedges) {
  __shared__ float sE[4][EPW][64];     // 4 KB
  __shared__ float sEA[4][EPW * 8];    // 0.5 KB: per-wave 4 edges x 8 attrs

  const int wv = threadIdx.x >> 6;
  const int j  = threadIdx.x & 63;
  const int ebase = (blockIdx.x * 4 + wv) * EPW;
  if (ebase >= nedges) return;

  // per-wave attr staging: lanes<32 coalesce-load 4 edges x 8 attrs.
  // same-wave LDS write -> read: in-order, no barrier needed.
  if (j < 32) {
    long long gi = (long long)ebase * 8 + j;
    long long gmax = (long long)nedges * 8 - 1;
    if (gi > gmax) gi = gmax;
    sEA[wv][j] = ea[gi];
  }

  // issue index loads + hw1/hw2 gathers first (long-latency, overlap embed)
  const float bj = msgB[j];
  int dIdx[EPW];
  float acc[EPW];
#pragma unroll
  for (int e = 0; e < EPW; ++e) {
    int ce = min(ebase + e, nedges - 1);
    int s = srcI[ce];
    dIdx[e] = dstI[ce];
    acc[e] = hw1[(size_t)dIdx[e] * 64 + j] + hw2[(size_t)s * 64 + j] + bj;
  }

  // edge embeddings from LDS-staged attrs (broadcast reads)
  {
    float ewc[8];
#pragma unroll
    for (int k = 0; k < 8; ++k) ewc[k] = eeW[k * 64 + j];
    const float eb = eeB[j], eg = eeG[j], ebe = eeBe[j];
#pragma unroll
    for (int e = 0; e < EPW; ++e) {
      const float* ar = &sEA[wv][e * 8];
      float ev = eb;
#pragma unroll
      for (int k = 0; k < 8; ++k) ev += ar[k] * ewc[k];
      ev = silu_f(ln64(ev, eg, ebe));
      sE[wv][e][j] = ev;   // same-wave write; same-wave read below -> ordered
    }
  }

  // MAC: acc[e] += e_vec @ W3 ; W3 from global, coalesced, L1-resident
#pragma unroll
  for (int k = 0; k < 64; k += 4) {
    float w0 = W3[(k + 0) * 64 + j];
    float w1 = W3[(k + 1) * 64 + j];
    float w2 = W3[(k + 2) * 64 + j];
    float w3 = W3[(k + 3) * 64 + j];
#pragma unroll
    for (int e = 0; e < EPW; ++e) {
      float4 ev4 = *(const float4*)&sE[wv][e][k];
      acc[e] += ev4.x * w0 + ev4.y * w1 + ev4.z * w2 + ev4.w * w3;
    }
  }

  // LN + silu + scatter-add
  {
    const float mg = msgG[j], mbe = msgBe[j];
#pragma unroll
    for (int e = 0; e < EPW; ++e) {
      float m = ln64(silu_f(acc[e]), mg, mbe);
      if (ebase + e < nedges) unsafeAtomicAdd(&agg[(size_t)dIdx[e] * 64 + j], m);
    }
  }
}

// ---------- update: hn = LN(LN(silu((h+agg)@W+b)) + h) ----------
__global__ __launch_bounds__(256) void k_node_update(
    const float* __restrict__ h, const float* __restrict__ agg,
    const float* __restrict__ W, const float* __restrict__ b,
    const float* __restrict__ ug, const float* __restrict__ ube,
    const float* __restrict__ ng, const float* __restrict__ nbe,
    float* __restrict__ hn, int n) {
  int row = (blockIdx.x * 256 + threadIdx.x) >> 6;
  int j = threadIdx.x & 63;
  if (row >= n) return;
  const float* hr = h + (size_t)row * 64;
  const float* ar = agg + (size_t)row * 64;
  float acc = b[j];
#pragma unroll
  for (int k = 0; k < 64; k += 4) {
    float4 hv = *(const float4*)&hr[k];
    float4 av = *(const float4*)&ar[k];
    acc += (hv.x + av.x) * W[(k + 0) * 64 + j] + (hv.y + av.y) * W[(k + 1) * 64 + j] +
           (hv.z + av.z) * W[(k + 2) * 64 + j] + (hv.w + av.w) * W[(k + 3) * 64 + j];
  }
  float u = ln64(silu_f(acc), ug[j], ube[j]);
  hn[(size_t)row * 64 + j] = ln64(u + hr[j], ng[j], nbe[j]);
}

// ---------- pooling ----------
__global__ __launch_bounds__(256) void k_pool(
    const float* __restrict__ h, const int* __restrict__ batch,
    float* __restrict__ gsum, float* __restrict__ gcnt, int n) {
  int row = (blockIdx.x * 256 + threadIdx.x) >> 6;
  int j = threadIdx.x & 63;
  if (row >= n) return;
  int b = batch[row];
  unsafeAtomicAdd(&gsum[(size_t)b * 64 + j], h[(size_t)row * 64 + j]);
  if (j == 0) unsafeAtomicAdd(&gcnt[b], 1.0f);
}

// ---------- head: out = silu(LN(g@h1_w+b)) @ h2_w + h2_b ----------
__global__ __launch_bounds__(64) void k_head(
    const float* __restrict__ gsum, const float* __restrict__ gcnt,
    const float* __restrict__ w1, const float* __restrict__ b1,
    const float* __restrict__ g1, const float* __restrict__ be1,
    const float* __restrict__ w2, const float* __restrict__ b2,
    float* __restrict__ out, int ngraphs) {
  int gidx = blockIdx.x;
  int j = threadIdx.x;
  if (gidx >= ngraphs) return;
  __shared__ float sg[64];
  float cnt = fmaxf(gcnt[gidx], 1.0f);
  sg[j] = gsum[(size_t)gidx * 64 + j] / cnt;
  float acc = 0.0f;
  if (j < 32) {
    acc = b1[j];
#pragma unroll 8
    for (int k = 0; k < 64; ++k) acc += sg[k] * w1[k * 32 + j];
  }
  float s = acc, s2 = acc * acc;
#pragma unroll
  for (int m = 16; m > 0; m >>= 1) {
    s  += __shfl_xor(s,  m, 64);
    s2 += __shfl_xor(s2, m, 64);
  }
  float mean = s * 0.03125f;
  float var  = fmaxf(s2 * 0.03125f - mean * mean, 0.0f);
  float z = 0.0f;
  if (j < 32) {
    float nv = (acc - mean) * rsqrtf(var + 1e-5f) * g1[j] + be1[j];
    z = silu_f(nv) * w2[j];
  }
  float tot = wsum64(z);
  if (j == 0) out[gidx] = tot + b2[0];
}

// ---------- launch ----------
extern "C" void kernel_launch(void* const* d_in, const int* in_sizes, int n_in,
                              void* d_out, int out_size, void* d_ws, size_t ws_size,
                              hipStream_t stream) {
  const float* x      = (const float*)d_in[0];
  const float* ea     = (const float*)d_in[1];
  const float* ne_w   = (const float*)d_in[2];
  const float* ne_b   = (const float*)d_in[3];
  const float* ne_g   = (const float*)d_in[4];
  const float* ne_be  = (const float*)d_in[5];
  const float* ee_w   = (const float*)d_in[6];
  const float* ee_b   = (const float*)d_in[7];
  const float* ee_g   = (const float*)d_in[8];
  const float* ee_be  = (const float*)d_in[9];
  const float* msg_w  = (const float*)d_in[10];
  const float* msg_b  = (const float*)d_in[11];
  const float* msg_g  = (const float*)d_in[12];
  const float* msg_be = (const float*)d_in[13];
  const float* upd_w  = (const float*)d_in[14];
  const float* upd_b  = (const float*)d_in[15];
  const float* upd_g  = (const float*)d_in[16];
  const float* upd_be = (const float*)d_in[17];
  const float* nrm_g  = (const float*)d_in[18];
  const float* nrm_be = (const float*)d_in[19];
  const float* h1_w   = (const float*)d_in[20];
  const float* h1_b   = (const float*)d_in[21];
  const float* h1_g   = (const float*)d_in[22];
  const float* h1_be  = (const float*)d_in[23];
  const float* h2_w   = (const float*)d_in[24];
  const float* h2_b   = (const float*)d_in[25];
  const int*   ei     = (const int*)d_in[26];
  const int*   batch  = (const int*)d_in[27];
  float* out = (float*)d_out;

  const int N = in_sizes[0] / 16;
  const int E = in_sizes[1] / 8;
  const int G = out_size;
  const int* srcI = ei;       // edge_index[0] = src (x_j)
  const int* dstI = ei + E;   // edge_index[1] = dst (x_i)

  float* ws  = (float*)d_ws;
  float* h    = ws;
  float* hn   = h   + (size_t)N * 64;
  float* hw1  = hn  + (size_t)N * 64;
  float* hw2  = hw1 + (size_t)N * 64;
  float* agg  = hw2 + (size_t)N * 64;
  float* gsum = agg + (size_t)N * 64;
  float* gcnt = gsum + (size_t)G * 64;

  const int nblk = (N + 3) / 4;                      // 4 node rows per block
  const int eblk = (E + 4 * EPW - 1) / (4 * EPW);    // 16 edges per block

  k_node_embed<<<nblk, 256, 0, stream>>>(x, ne_w, ne_b, ne_g, ne_be, h, N);

  float* hcur = h;
  float* hnext = hn;
  for (int l = 0; l < 2; ++l) {
    const float* Wl = msg_w + (size_t)l * 192 * 64;
    k_node_msgw<<<nblk, 256, 0, stream>>>(hcur, Wl, hw1, hw2, N);
    hipMemsetAsync(agg, 0, (size_t)N * 64 * sizeof(float), stream);
    k_edge_msg<<<eblk, 256, 0, stream>>>(
        ea, ee_w, ee_b, ee_g, ee_be,
        Wl + 128 * 64, msg_b + l * 64, msg_g + l * 64, msg_be + l * 64,
        hw1, hw2, srcI, dstI, agg, E);
    k_node_update<<<nblk, 256, 0, stream>>>(
        hcur, agg, upd_w + (size_t)l * 64 * 64,
        upd_b + l * 64, upd_g + l * 64, upd_be + l * 64,
        nrm_g + l * 64, nrm_be + l * 64, hnext, N);
    float* t = hcur; hcur = hnext; hnext = t;
  }

  hipMemsetAsync(gsum, 0, ((size_t)G * 64 + G) * sizeof(float), stream);
  k_pool<<<nblk, 256, 0, stream>>>(hcur, batch, gsum, gcnt, N);
  k_head<<<G, 64, 0, stream>>>(gsum, gcnt, h1_w, h1_b, h1_g, h1_be, h2_w, h2_b, out, G);
}